// Round 7
// baseline (302.417 us; speedup 1.0000x reference)
//
#include <hip/hip_runtime.h>
#include <hip/hip_bf16.h>

// ---------- types ----------
typedef __attribute__((ext_vector_type(8))) short s16x8;   // 8 x bf16 (4 VGPR)
typedef __attribute__((ext_vector_type(4))) float f32x4;   // MFMA acc

#define B_SZ 64
#define T_SZ 2000
#define QD 1024
#define MD 512
#define AD 128
#define NF 32
#define KW 31
#define NTILE 63
#define ASTRIDE 1056   // Atile row stride in BYTES (264 words == 8 mod 32 banks)

// ---------- helpers ----------
__device__ __forceinline__ unsigned short f2bf(float f) {
    unsigned int u = __float_as_uint(f);
    unsigned int r = (u + 0x7FFFu + ((u >> 16) & 1u)) >> 16;  // RNE
    return (unsigned short)r;
}
__device__ __forceinline__ unsigned int pack2bf_manual(float a, float b) {
    return (unsigned int)f2bf(a) | ((unsigned int)f2bf(b) << 16);
}
__device__ __forceinline__ unsigned int pack2bf(float a, float b) {
    union { __hip_bfloat162 h; unsigned int u; } cv;
    cv.h = __float22bfloat162_rn(float2{a, b});
    return cv.u;
}
__device__ __forceinline__ float fast_tanh(float x) {
    float ax = fabsf(x);
    float e = __expf(2.0f * ax);
    float r = 1.0f - 2.0f * __builtin_amdgcn_rcpf(e + 1.0f);
    return x < 0.0f ? -r : r;
}

// ---------- kernel A: pq + weight packing ----------
__global__ __launch_bounds__(512) void prep_kernel(
    const float* __restrict__ ahs, const float* __restrict__ Wq,
    const float* __restrict__ Wm, const float* __restrict__ Wl,
    float* __restrict__ pq, unsigned short* __restrict__ WB,
    unsigned short* __restrict__ WL) {
    const int blk = blockIdx.x, tid = threadIdx.x;
    if (blk < 64) {
        __shared__ float q_sm[QD];
        __shared__ float part[3][AD];
        ((float2*)q_sm)[tid] = ((const float2*)(ahs + blk * QD))[tid];
        __syncthreads();
        const int d = tid & 127, kh = tid >> 7;
        const int k0 = kh * 256;
        float a0 = 0, a1 = 0, a2 = 0, a3 = 0;
        #pragma unroll 4
        for (int k = k0; k < k0 + 256; k += 4) {
            a0 += q_sm[k]     * Wq[(k)     * AD + d];
            a1 += q_sm[k + 1] * Wq[(k + 1) * AD + d];
            a2 += q_sm[k + 2] * Wq[(k + 2) * AD + d];
            a3 += q_sm[k + 3] * Wq[(k + 3) * AD + d];
        }
        float s = (a0 + a1) + (a2 + a3);
        if (kh) part[kh - 1][d] = s;
        __syncthreads();
        if (tid < AD)
            pq[blk * AD + tid] =
                fast_tanh((s + part[0][tid]) + (part[1][tid] + part[2][tid]));
    } else if (blk < 80) {
        int cidx = (blk - 64) * 512 + tid;        // 0..8191 = (n,s,l)
        int n = cidx >> 10, s = (cidx >> 6) & 15, l = cidx & 63;
        int col = n * 16 + (l & 15);
        int krow = s * 32 + (l >> 4) * 8;
        float v[8];
        #pragma unroll
        for (int j = 0; j < 8; ++j) v[j] = Wm[(krow + j) * AD + col];
        uint4 pk;
        pk.x = pack2bf(v[0], v[1]); pk.y = pack2bf(v[2], v[3]);
        pk.z = pack2bf(v[4], v[5]); pk.w = pack2bf(v[6], v[7]);
        *(uint4*)(WB + cidx * 8) = pk;
    } else {
        int cidx = tid;                            // 0..511 = (n,l)
        int n = cidx >> 6, l = cidx & 63;
        int col = n * 16 + (l & 15);
        int krow = (l >> 4) * 8;
        float v[8];
        #pragma unroll
        for (int j = 0; j < 8; ++j) v[j] = Wl[(krow + j) * AD + col];
        uint4 pk;
        pk.x = pack2bf_manual(v[0], v[1]); pk.y = pack2bf_manual(v[2], v[3]);
        pk.z = pack2bf_manual(v[4], v[5]); pk.w = pack2bf_manual(v[6], v[7]);
        *(uint4*)(WL + cidx * 8) = pk;
    }
}

// ---------- energy kernel helpers ----------
__device__ __forceinline__ void prefetch_half(
    const float* memory, int b, int tile, int tid, float4 (&v)[8]) {
    // rows 0..15 of tile (always fully in-bounds: 62*32+16 == 2000)
    const float4* msrc = (const float4*)(memory + ((size_t)b * T_SZ + tile * 32) * MD);
    #pragma unroll
    for (int it = 0; it < 4; ++it) {
        int cid = it * 256 + tid;
        int r = cid >> 6, cc = cid & 63;
        v[2 * it]     = msrc[r * 128 + cc * 2];
        v[2 * it + 1] = msrc[r * 128 + cc * 2 + 1];
    }
}

__device__ __forceinline__ void tile_body(
    int b, int tile, int tid,
    const float* __restrict__ memory, const float* __restrict__ awcat,
    const float* __restrict__ Wconv,
    const unsigned short* __restrict__ WB, const unsigned short* __restrict__ WL,
    float pqv0, float pqv1, float wvv0, float wvv1,
    float* __restrict__ wts, float* __restrict__ ctile,
    float* __restrict__ mloc, float* __restrict__ Stile,
    unsigned short* Atile, float (*aw_sm)[64], unsigned short* conv_sm,
    float (*e_part)[4], float* p_sm,
    float4 (&vin)[8], float4 (&vnext)[8], bool doPref) {
    const int t0 = tile * 32;
    const float4* msrc = (const float4*)(memory + ((size_t)b * T_SZ + t0) * MD);
    char* Ac = (char*)Atile;

    // issue second-half loads (rows 16..31)
    float4 v2[8];
    if (t0 + 32 <= T_SZ) {
        #pragma unroll
        for (int it = 0; it < 4; ++it) {
            int cid = it * 256 + tid;
            int r = 16 + (cid >> 6), cc = cid & 63;
            v2[2 * it]     = msrc[r * 128 + cc * 2];
            v2[2 * it + 1] = msrc[r * 128 + cc * 2 + 1];
        }
    } else {
        #pragma unroll
        for (int it = 0; it < 4; ++it) {
            int cid = it * 256 + tid;
            int r = 16 + (cid >> 6), cc = cid & 63;
            float4 z = {0, 0, 0, 0};
            bool ok = (t0 + r) < T_SZ;
            v2[2 * it]     = ok ? msrc[r * 128 + cc * 2]     : z;
            v2[2 * it + 1] = ok ? msrc[r * 128 + cc * 2 + 1] : z;
        }
    }

    // awc slice loads
    float awv = 0.0f;
    const int awc_c = tid >> 6, awc_i = tid & 63;
    if (tid < 128) {
        int tv = t0 - 15 + awc_i;
        if (awc_i < 63 && tv >= 0 && tv < T_SZ) awv = awcat[(b * 2 + awc_c) * T_SZ + tv];
    }

    // write first half (prefetched) then second half
    #pragma unroll
    for (int it = 0; it < 4; ++it) {
        int cid = it * 256 + tid;
        int r = cid >> 6, cc = cid & 63;
        float4 a0 = vin[2 * it], a1 = vin[2 * it + 1];
        uint4 pk;
        pk.x = pack2bf(a0.x, a0.y); pk.y = pack2bf(a0.z, a0.w);
        pk.z = pack2bf(a1.x, a1.y); pk.w = pack2bf(a1.z, a1.w);
        *(uint4*)(Ac + r * ASTRIDE + ((cc * 16) ^ ((r & 7) << 4))) = pk;
    }
    #pragma unroll
    for (int it = 0; it < 4; ++it) {
        int cid = it * 256 + tid;
        int r = 16 + (cid >> 6), cc = cid & 63;
        float4 a0 = v2[2 * it], a1 = v2[2 * it + 1];
        uint4 pk;
        pk.x = pack2bf(a0.x, a0.y); pk.y = pack2bf(a0.z, a0.w);
        pk.z = pack2bf(a1.x, a1.y); pk.w = pack2bf(a1.z, a1.w);
        *(uint4*)(Ac + r * ASTRIDE + ((cc * 16) ^ ((r & 7) << 4))) = pk;
    }
    if (tid < 128) aw_sm[awc_c][awc_i] = awv;
    __syncthreads();

    // prefetch next tile's first half — in flight through all compute phases
    if (doPref) prefetch_half(memory, b, tile + 1, tid, vnext);

    // conv1d: thread = (f = tid&31, tq = tid>>5); 4 t's per thread
    {
        int f = tid & 31, tq = tid >> 5;
        float acc[4] = {0, 0, 0, 0};
        for (int k = 0; k < KW; ++k) {
            #pragma unroll
            for (int c = 0; c < 2; ++c) {
                float wv = Wconv[(k * 2 + c) * NF + f];
                #pragma unroll
                for (int tt = 0; tt < 4; ++tt)
                    acc[tt] += wv * aw_sm[c][tq + tt * 8 + k];
            }
        }
        #pragma unroll
        for (int tt = 0; tt < 4; ++tt)
            conv_sm[(tq + tt * 8) * 40 + f] = f2bf(acc[tt]);
    }
    __syncthreads();

    // MFMA phase
    const int w = tid >> 6, l = tid & 63;
    const int lr = l & 15, lg = l >> 4;

    f32x4 zero4 = {0, 0, 0, 0};
    f32x4 p00 = zero4, p01 = zero4, p10 = zero4, p11 = zero4;

    const s16x8* wbp = (const s16x8*)WB;
    const int swz = (lr & 7) << 4;
    const int rbase0 = lr * ASTRIDE;
    const int rbase1 = (16 + lr) * ASTRIDE;
    const int inb = lg * 16;

    #pragma unroll
    for (int s = 0; s < 16; ++s) {
        int j = (inb + s * 64) ^ swz;
        s16x8 a0 = *(const s16x8*)(Ac + rbase0 + j);
        s16x8 a1 = *(const s16x8*)(Ac + rbase1 + j);
        s16x8 b0 = wbp[((2 * w + 0) * 16 + s) * 64 + l];
        s16x8 b1 = wbp[((2 * w + 1) * 16 + s) * 64 + l];
        p00 = __builtin_amdgcn_mfma_f32_16x16x32_bf16(a0, b0, p00, 0, 0, 0);
        p01 = __builtin_amdgcn_mfma_f32_16x16x32_bf16(a0, b1, p01, 0, 0, 0);
        p10 = __builtin_amdgcn_mfma_f32_16x16x32_bf16(a1, b0, p10, 0, 0, 0);
        p11 = __builtin_amdgcn_mfma_f32_16x16x32_bf16(a1, b1, p11, 0, 0, 0);
    }

    // ploc MFMA (K=32, one step)
    s16x8 la0 = *(const s16x8*)((const char*)conv_sm + (lr * 80 + lg * 16));
    s16x8 la1 = *(const s16x8*)((const char*)conv_sm + ((16 + lr) * 80 + lg * 16));
    const s16x8* wlp = (const s16x8*)WL;
    s16x8 lb0 = wlp[(2 * w + 0) * 64 + l];
    s16x8 lb1 = wlp[(2 * w + 1) * 64 + l];
    f32x4 q00 = __builtin_amdgcn_mfma_f32_16x16x32_bf16(la0, lb0, zero4, 0, 0, 0);
    f32x4 q01 = __builtin_amdgcn_mfma_f32_16x16x32_bf16(la0, lb1, zero4, 0, 0, 0);
    f32x4 q10 = __builtin_amdgcn_mfma_f32_16x16x32_bf16(la1, lb0, zero4, 0, 0, 0);
    f32x4 q11 = __builtin_amdgcn_mfma_f32_16x16x32_bf16(la1, lb1, zero4, 0, 0, 0);

    // epilogue
    float vr[8];
    #pragma unroll
    for (int r = 0; r < 4; ++r) {
        vr[r]     = fast_tanh(pqv0 + fast_tanh(q00[r]) + fast_tanh(p00[r])) * wvv0
                  + fast_tanh(pqv1 + fast_tanh(q01[r]) + fast_tanh(p01[r])) * wvv1;
        vr[4 + r] = fast_tanh(pqv0 + fast_tanh(q10[r]) + fast_tanh(p10[r])) * wvv0
                  + fast_tanh(pqv1 + fast_tanh(q11[r]) + fast_tanh(p11[r])) * wvv1;
    }
    #pragma unroll
    for (int j = 0; j < 8; ++j) {
        float vv = vr[j];
        vv += __shfl_xor(vv, 1);
        vv += __shfl_xor(vv, 2);
        vv += __shfl_xor(vv, 4);
        vv += __shfl_xor(vv, 8);
        if (lr == 0) e_part[(j >> 2) * 16 + lg * 4 + (j & 3)][w] = vv;
    }
    __syncthreads();

    if (tid < 32) {
        int t = t0 + tid;
        bool valid = t < T_SZ;
        float e = (e_part[tid][0] + e_part[tid][1]) + (e_part[tid][2] + e_part[tid][3]);
        float m = valid ? e : -3.4e38f;
        m = fmaxf(m, __shfl_xor(m, 1));
        m = fmaxf(m, __shfl_xor(m, 2));
        m = fmaxf(m, __shfl_xor(m, 4));
        m = fmaxf(m, __shfl_xor(m, 8));
        m = fmaxf(m, __shfl_xor(m, 16));
        float p = valid ? __expf(e - m) : 0.0f;
        p_sm[tid] = p;
        float S = p;
        S += __shfl_xor(S, 1);
        S += __shfl_xor(S, 2);
        S += __shfl_xor(S, 4);
        S += __shfl_xor(S, 8);
        S += __shfl_xor(S, 16);
        if (valid) wts[b * T_SZ + t] = p;
        if (tid == 0) { mloc[b * NTILE + tile] = m; Stile[b * NTILE + tile] = S; }
    }
    __syncthreads();

    // ctx partial: thread owns d = 2*tid, 2*tid+1
    {
        float c0 = 0.0f, c1 = 0.0f;
        const int boff = tid * 4;
        #pragma unroll
        for (int t = 0; t < 32; ++t) {
            float p = p_sm[t];
            unsigned int pk = *(const unsigned int*)(
                Ac + t * ASTRIDE + (boff ^ ((t & 7) << 4)));
            c0 += p * __uint_as_float(pk << 16);
            c1 += p * __uint_as_float(pk & 0xffff0000u);
        }
        float2 o; o.x = c0; o.y = c1;
        ((float2*)ctile)[((b * NTILE + tile) << 8) + tid] = o;
    }
    __syncthreads();   // Atile free for next tile
}

// ---------- kernel B: persistent 4-tile pipelined blocks ----------
// grid (16, 64); block 256 (4 waves). block gx owns tiles 4gx..4gx+3 (gx 15: 3).
__global__ __launch_bounds__(256, 4) void energy_kernel(
    const float* __restrict__ memory, const float* __restrict__ awcat,
    const float* __restrict__ Wconv, const float* __restrict__ Wv,
    const float* __restrict__ pq, const unsigned short* __restrict__ WB,
    const unsigned short* __restrict__ WL, float* __restrict__ wts,
    float* __restrict__ ctile, float* __restrict__ mloc,
    float* __restrict__ Stile) {
    const int gx = blockIdx.x;
    const int b = blockIdx.y;
    const int tbase = gx * 4;
    const int ntiles = (tbase + 4 <= NTILE) ? 4 : (NTILE - tbase);
    const int tid = threadIdx.x;

    __shared__ __align__(16) unsigned short Atile[32 * (ASTRIDE / 2)];
    __shared__ float aw_sm[2][64];
    __shared__ __align__(16) unsigned short conv_sm[32 * 40];
    __shared__ float e_part[32][4];
    __shared__ float p_sm[32];

    // hoisted per-batch constants
    const int w = tid >> 6, lr = tid & 15;
    const int d0 = (2 * w + 0) * 16 + lr;
    const int d1 = (2 * w + 1) * 16 + lr;
    const float pqv0 = pq[b * AD + d0], pqv1 = pq[b * AD + d1];
    const float wvv0 = Wv[d0], wvv1 = Wv[d1];

    float4 vA[8], vB[8];
    prefetch_half(memory, b, tbase, tid, vA);

    tile_body(b, tbase + 0, tid, memory, awcat, Wconv, WB, WL,
              pqv0, pqv1, wvv0, wvv1, wts, ctile, mloc, Stile,
              Atile, aw_sm, conv_sm, e_part, p_sm, vA, vB, ntiles > 1);
    if (ntiles > 1)
        tile_body(b, tbase + 1, tid, memory, awcat, Wconv, WB, WL,
                  pqv0, pqv1, wvv0, wvv1, wts, ctile, mloc, Stile,
                  Atile, aw_sm, conv_sm, e_part, p_sm, vB, vA, ntiles > 2);
    if (ntiles > 2)
        tile_body(b, tbase + 2, tid, memory, awcat, Wconv, WB, WL,
                  pqv0, pqv1, wvv0, wvv1, wts, ctile, mloc, Stile,
                  Atile, aw_sm, conv_sm, e_part, p_sm, vA, vB, ntiles > 3);
    if (ntiles > 3)
        tile_body(b, tbase + 3, tid, memory, awcat, Wconv, WB, WL,
                  pqv0, pqv1, wvv0, wvv1, wts, ctile, mloc, Stile,
                  Atile, aw_sm, conv_sm, e_part, p_sm, vB, vA, false);
}

// ---------- kernel C: finalize (global M,Z; rescale wts; reduce ctx) ----------
__global__ __launch_bounds__(256) void finalize_kernel(
    const float* __restrict__ mloc, const float* __restrict__ Stile,
    const float* __restrict__ ctile, float* __restrict__ wts,
    float* __restrict__ ctx) {
    const int b = blockIdx.x, h = blockIdx.y, tid = threadIdx.x;
    __shared__ float sc_sm[NTILE + 1];
    if (tid < 64) {
        float m = (tid < NTILE) ? mloc[b * NTILE + tid] : -3.4e38f;
        float s = (tid < NTILE) ? Stile[b * NTILE + tid] : 0.0f;
        float M = m;
        M = fmaxf(M, __shfl_xor(M, 1));  M = fmaxf(M, __shfl_xor(M, 2));
        M = fmaxf(M, __shfl_xor(M, 4));  M = fmaxf(M, __shfl_xor(M, 8));
        M = fmaxf(M, __shfl_xor(M, 16)); M = fmaxf(M, __shfl_xor(M, 32));
        float e = __expf(m - M);
        float z = e * s;
        z += __shfl_xor(z, 1);  z += __shfl_xor(z, 2);
        z += __shfl_xor(z, 4);  z += __shfl_xor(z, 8);
        z += __shfl_xor(z, 16); z += __shfl_xor(z, 32);
        if (tid < NTILE) sc_sm[tid] = e / z;
    }
    __syncthreads();

    if (h == 0) {
        #pragma unroll
        for (int i = 0; i < 8; ++i) {
            int idx = tid + i * 256;
            if (idx < T_SZ) wts[b * T_SZ + idx] *= sc_sm[idx >> 5];
        }
    }

    float a = 0.0f;
    const float* cb = ctile + ((size_t)b * NTILE << 9) + h * 256 + tid;
    #pragma unroll 7
    for (int tl = 0; tl < NTILE; ++tl) a += sc_sm[tl] * cb[(size_t)tl << 9];
    ctx[b * MD + h * 256 + tid] = a;
}

// ---------- launch ----------
extern "C" void kernel_launch(void* const* d_in, const int* in_sizes, int n_in,
                              void* d_out, int out_size, void* d_ws, size_t ws_size,
                              hipStream_t stream) {
    const float* ahs    = (const float*)d_in[0];
    const float* memory = (const float*)d_in[1];
    const float* awcat  = (const float*)d_in[2];
    const float* Wq     = (const float*)d_in[3];
    const float* Wm     = (const float*)d_in[4];
    const float* Wv     = (const float*)d_in[5];
    const float* Wconv  = (const float*)d_in[6];
    const float* Wl     = (const float*)d_in[7];

    float* out = (float*)d_out;
    float* ctx = out;                 // [64][512]
    float* wts = out + B_SZ * MD;     // [64][2000]

    char* ws = (char*)d_ws;
    float* pq             = (float*)(ws);                    // 32 KB
    unsigned short* WB    = (unsigned short*)(ws + 32768);   // 128 KB
    unsigned short* WL    = (unsigned short*)(ws + 163840);  // 8 KB
    float* mloc           = (float*)(ws + 172032);           // 15.75 KB
    float* Stile          = (float*)(ws + 188160);           // 15.75 KB
    float* ctile          = (float*)(ws + 204800);           // 8.25 MB

    prep_kernel<<<81, 512, 0, stream>>>(ahs, Wq, Wm, Wl, pq, WB, WL);
    energy_kernel<<<dim3(16, B_SZ), 256, 0, stream>>>(
        memory, awcat, Wconv, Wv, pq, WB, WL, wts, ctile, mloc, Stile);
    finalize_kernel<<<dim3(B_SZ, 2), 256, 0, stream>>>(mloc, Stile, ctile, wts, ctx);
}

// Round 8
// 103.382 us; speedup vs baseline: 2.9252x; 2.9252x over previous
//
#include <hip/hip_runtime.h>
#include <hip/hip_bf16.h>

// ---------- types ----------
typedef __attribute__((ext_vector_type(8))) short s16x8;   // 8 x bf16 (4 VGPR)
typedef __attribute__((ext_vector_type(4))) float f32x4;   // MFMA acc

#define B_SZ 64
#define T_SZ 2000
#define QD 1024
#define MD 512
#define AD 128
#define NF 32
#define KW 31
#define TT 16          // t-rows per tile; 2000 = 125 * 16 exactly (no tails)
#define NTILE 125
#define ASTRIDE 1056   // Atile row stride in BYTES (264 words == 8 mod 32 banks)

// ---------- helpers ----------
__device__ __forceinline__ unsigned short f2bf(float f) {
    unsigned int u = __float_as_uint(f);
    unsigned int r = (u + 0x7FFFu + ((u >> 16) & 1u)) >> 16;  // RNE
    return (unsigned short)r;
}
__device__ __forceinline__ unsigned int pack2bf_manual(float a, float b) {
    return (unsigned int)f2bf(a) | ((unsigned int)f2bf(b) << 16);
}
__device__ __forceinline__ unsigned int pack2bf(float a, float b) {
    union { __hip_bfloat162 h; unsigned int u; } cv;
    cv.h = __float22bfloat162_rn(float2{a, b});
    return cv.u;
}
__device__ __forceinline__ float fast_tanh(float x) {
    float ax = fabsf(x);
    float e = __expf(2.0f * ax);
    float r = 1.0f - 2.0f * __builtin_amdgcn_rcpf(e + 1.0f);
    return x < 0.0f ? -r : r;
}

// ---------- kernel A: pq + weight packing (unchanged from R6) ----------
__global__ __launch_bounds__(512) void prep_kernel(
    const float* __restrict__ ahs, const float* __restrict__ Wq,
    const float* __restrict__ Wm, const float* __restrict__ Wl,
    float* __restrict__ pq, unsigned short* __restrict__ WB,
    unsigned short* __restrict__ WL) {
    const int blk = blockIdx.x, tid = threadIdx.x;
    if (blk < 64) {
        __shared__ float q_sm[QD];
        __shared__ float part[3][AD];
        ((float2*)q_sm)[tid] = ((const float2*)(ahs + blk * QD))[tid];
        __syncthreads();
        const int d = tid & 127, kh = tid >> 7;
        const int k0 = kh * 256;
        float a0 = 0, a1 = 0, a2 = 0, a3 = 0;
        #pragma unroll 4
        for (int k = k0; k < k0 + 256; k += 4) {
            a0 += q_sm[k]     * Wq[(k)     * AD + d];
            a1 += q_sm[k + 1] * Wq[(k + 1) * AD + d];
            a2 += q_sm[k + 2] * Wq[(k + 2) * AD + d];
            a3 += q_sm[k + 3] * Wq[(k + 3) * AD + d];
        }
        float s = (a0 + a1) + (a2 + a3);
        if (kh) part[kh - 1][d] = s;
        __syncthreads();
        if (tid < AD)
            pq[blk * AD + tid] =
                fast_tanh((s + part[0][tid]) + (part[1][tid] + part[2][tid]));
    } else if (blk < 80) {
        int cidx = (blk - 64) * 512 + tid;        // 0..8191 = (n,s,l)
        int n = cidx >> 10, s = (cidx >> 6) & 15, l = cidx & 63;
        int col = n * 16 + (l & 15);
        int krow = s * 32 + (l >> 4) * 8;
        float v[8];
        #pragma unroll
        for (int j = 0; j < 8; ++j) v[j] = Wm[(krow + j) * AD + col];
        uint4 pk;
        pk.x = pack2bf(v[0], v[1]); pk.y = pack2bf(v[2], v[3]);
        pk.z = pack2bf(v[4], v[5]); pk.w = pack2bf(v[6], v[7]);
        *(uint4*)(WB + cidx * 8) = pk;
    } else {
        int cidx = tid;                            // 0..511 = (n,l)
        int n = cidx >> 6, l = cidx & 63;
        int col = n * 16 + (l & 15);
        int krow = (l >> 4) * 8;
        float v[8];
        #pragma unroll
        for (int j = 0; j < 8; ++j) v[j] = Wl[(krow + j) * AD + col];
        uint4 pk;
        pk.x = pack2bf_manual(v[0], v[1]); pk.y = pack2bf_manual(v[2], v[3]);
        pk.z = pack2bf_manual(v[4], v[5]); pk.w = pack2bf_manual(v[6], v[7]);
        *(uint4*)(WL + cidx * 8) = pk;
    }
}

// ---------- kernel B: 16-row tiles, grid (125, 64), block 256 (4 waves) ----------
// LDS ~19 KB/block -> 6-8 blocks/CU for phase overlap via TLP.
__global__ __launch_bounds__(256, 6) void energy_kernel(
    const float* __restrict__ memory, const float* __restrict__ awcat,
    const float* __restrict__ Wconv, const float* __restrict__ Wv,
    const float* __restrict__ pq, const unsigned short* __restrict__ WB,
    const unsigned short* __restrict__ WL, float* __restrict__ wts,
    float* __restrict__ ctile, float* __restrict__ mloc,
    float* __restrict__ Stile, int do_fuse) {
    const int tile = blockIdx.x;
    const int b = blockIdx.y;
    const int t0 = tile * TT;
    const int tid = threadIdx.x;

    __shared__ __align__(16) unsigned short Atile[TT * (ASTRIDE / 2)]; // 16.9 KB
    __shared__ float aw_sm[2][64];
    __shared__ __align__(16) unsigned short conv_sm[TT * 40];          // 1.25 KB
    __shared__ float e_part[TT][4];
    __shared__ float p_sm[TT];

    // stage memory tile (16 x 512 fp32) -> bf16 LDS, swizzled. No bounds checks.
    {
        const float4* msrc = (const float4*)(memory + ((size_t)b * T_SZ + t0) * MD);
        #pragma unroll
        for (int it = 0; it < 4; ++it) {
            int cid = it * 256 + tid;          // 1024 chunks of 8 floats
            int r = cid >> 6, cc = cid & 63;
            float4 v0 = msrc[r * 128 + cc * 2];
            float4 v1 = msrc[r * 128 + cc * 2 + 1];
            uint4 pk;
            pk.x = pack2bf(v0.x, v0.y); pk.y = pack2bf(v0.z, v0.w);
            pk.z = pack2bf(v1.x, v1.y); pk.w = pack2bf(v1.z, v1.w);
            int off = r * ASTRIDE + ((cc * 16) ^ ((r & 7) << 4));
            *(uint4*)((char*)Atile + off) = pk;
        }
    }

    // awc slice: i=0..45 -> t = t0-15+i (zero pad OOB)
    if (tid < 128) {
        int c = tid >> 6, i = tid & 63;
        float v = 0.0f;
        int tv = t0 - 15 + i;
        if (i < 46 && tv >= 0 && tv < T_SZ) v = awcat[(b * 2 + c) * T_SZ + tv];
        aw_sm[c][i] = v;
    }
    __syncthreads();

    // conv1d: thread = (f = tid&31, tq = tid>>5 in 0..7); 2 t's per thread
    {
        int f = tid & 31, tq = tid >> 5;
        float acc[2] = {0, 0};
        for (int k = 0; k < KW; ++k) {
            #pragma unroll
            for (int c = 0; c < 2; ++c) {
                float wv = Wconv[(k * 2 + c) * NF + f];
                acc[0] += wv * aw_sm[c][tq + k];
                acc[1] += wv * aw_sm[c][tq + 8 + k];
            }
        }
        conv_sm[(tq)     * 40 + f] = f2bf(acc[0]);
        conv_sm[(tq + 8) * 40 + f] = f2bf(acc[1]);
    }
    __syncthreads();

    // MFMA phase: wave w owns d-chunks 2w, 2w+1
    const int w = tid >> 6, l = tid & 63;
    const int lr = l & 15, lg = l >> 4;
    const int d0 = (2 * w + 0) * 16 + lr;
    const int d1 = (2 * w + 1) * 16 + lr;
    const float pqv0 = pq[b * AD + d0], pqv1 = pq[b * AD + d1];
    const float wvv0 = Wv[d0], wvv1 = Wv[d1];

    f32x4 zero4 = {0, 0, 0, 0};
    f32x4 p00 = zero4, p01 = zero4;

    const s16x8* wbp = (const s16x8*)WB;
    const int swz = (lr & 7) << 4;
    const int rbase = lr * ASTRIDE;
    const int inb = lg * 16;
    const char* Ac = (const char*)Atile;

    #pragma unroll
    for (int s = 0; s < 16; ++s) {
        int j = (inb + s * 64) ^ swz;
        s16x8 a0 = *(const s16x8*)(Ac + rbase + j);
        s16x8 b0 = wbp[((2 * w + 0) * 16 + s) * 64 + l];
        s16x8 b1 = wbp[((2 * w + 1) * 16 + s) * 64 + l];
        p00 = __builtin_amdgcn_mfma_f32_16x16x32_bf16(a0, b0, p00, 0, 0, 0);
        p01 = __builtin_amdgcn_mfma_f32_16x16x32_bf16(a0, b1, p01, 0, 0, 0);
    }

    // ploc MFMA (K=32, one step)
    s16x8 la0 = *(const s16x8*)((const char*)conv_sm + (lr * 80 + lg * 16));
    const s16x8* wlp = (const s16x8*)WL;
    s16x8 lb0 = wlp[(2 * w + 0) * 64 + l];
    s16x8 lb1 = wlp[(2 * w + 1) * 64 + l];
    f32x4 q00 = __builtin_amdgcn_mfma_f32_16x16x32_bf16(la0, lb0, zero4, 0, 0, 0);
    f32x4 q01 = __builtin_amdgcn_mfma_f32_16x16x32_bf16(la0, lb1, zero4, 0, 0, 0);

    // epilogue: e[t] partial = sum_d tanh(pq + tanh(ploc) + tanh(pm)) * Wv
    #pragma unroll
    for (int r = 0; r < 4; ++r) {
        float v = fast_tanh(pqv0 + fast_tanh(q00[r]) + fast_tanh(p00[r])) * wvv0
                + fast_tanh(pqv1 + fast_tanh(q01[r]) + fast_tanh(p01[r])) * wvv1;
        v += __shfl_xor(v, 1);
        v += __shfl_xor(v, 2);
        v += __shfl_xor(v, 4);
        v += __shfl_xor(v, 8);
        if (lr == 0) e_part[lg * 4 + r][w] = v;
    }
    __syncthreads();

    // tile softmax numerators (16 t's, lanes 0..15 of wave 0)
    if (tid < TT) {
        float e = (e_part[tid][0] + e_part[tid][1]) + (e_part[tid][2] + e_part[tid][3]);
        float m = e;
        m = fmaxf(m, __shfl_xor(m, 1));
        m = fmaxf(m, __shfl_xor(m, 2));
        m = fmaxf(m, __shfl_xor(m, 4));
        m = fmaxf(m, __shfl_xor(m, 8));
        float p = __expf(e - m);
        p_sm[tid] = p;
        float S = p;
        S += __shfl_xor(S, 1);
        S += __shfl_xor(S, 2);
        S += __shfl_xor(S, 4);
        S += __shfl_xor(S, 8);
        wts[b * T_SZ + t0 + tid] = p;
        if (tid == 0) { mloc[b * NTILE + tile] = m; Stile[b * NTILE + tile] = S; }
    }
    __syncthreads();

    // ctx partial: thread owns d = 2*tid, 2*tid+1 (rows still resident in LDS)
    if (do_fuse) {
        float c0 = 0.0f, c1 = 0.0f;
        const int boff = tid * 4;
        #pragma unroll
        for (int t = 0; t < TT; ++t) {
            float p = p_sm[t];
            unsigned int pk = *(const unsigned int*)(
                Ac + t * ASTRIDE + (boff ^ ((t & 7) << 4)));
            c0 += p * __uint_as_float(pk << 16);
            c1 += p * __uint_as_float(pk & 0xffff0000u);
        }
        float2 o; o.x = c0; o.y = c1;
        ((float2*)ctile)[((b * NTILE + tile) << 8) + tid] = o;
    }
}

// ---------- kernel C: finalize (global M,Z from 125 (m,S); rescale wts; ctx) ----------
// grid (64, 2); block 256. h = m-dim half.
__global__ __launch_bounds__(256) void finalize_kernel(
    const float* __restrict__ mloc, const float* __restrict__ Stile,
    const float* __restrict__ ctile, float* __restrict__ wts,
    float* __restrict__ ctx, int do_fuse) {
    const int b = blockIdx.x, h = blockIdx.y, tid = threadIdx.x;
    __shared__ float sc_sm[128];
    if (tid < 64) {
        float ma = mloc[b * NTILE + tid];
        float sa = Stile[b * NTILE + tid];
        bool hasb = (tid + 64) < NTILE;
        float mb = hasb ? mloc[b * NTILE + tid + 64] : -3.4e38f;
        float sb = hasb ? Stile[b * NTILE + tid + 64] : 0.0f;
        float M = fmaxf(ma, mb);
        M = fmaxf(M, __shfl_xor(M, 1));  M = fmaxf(M, __shfl_xor(M, 2));
        M = fmaxf(M, __shfl_xor(M, 4));  M = fmaxf(M, __shfl_xor(M, 8));
        M = fmaxf(M, __shfl_xor(M, 16)); M = fmaxf(M, __shfl_xor(M, 32));
        float ea = __expf(ma - M), eb = hasb ? __expf(mb - M) : 0.0f;
        float z = ea * sa + eb * sb;
        z += __shfl_xor(z, 1);  z += __shfl_xor(z, 2);
        z += __shfl_xor(z, 4);  z += __shfl_xor(z, 8);
        z += __shfl_xor(z, 16); z += __shfl_xor(z, 32);
        float inv = 1.0f / z;
        sc_sm[tid] = ea * inv;
        sc_sm[tid + 64] = eb * inv;
    }
    __syncthreads();

    if (h == 0) {
        #pragma unroll
        for (int i = 0; i < 8; ++i) {
            int idx = tid + i * 256;
            if (idx < T_SZ) wts[b * T_SZ + idx] *= sc_sm[idx >> 4];
        }
    }

    if (do_fuse) {
        float a = 0.0f;
        const float* cb = ctile + ((size_t)b * NTILE << 9) + h * 256 + tid;
        #pragma unroll 5
        for (int tl = 0; tl < NTILE; ++tl) a += sc_sm[tl] * cb[(size_t)tl << 9];
        ctx[b * MD + h * 256 + tid] = a;
    }
}

// ---------- fallback ctx kernels (two-pass; only if ws too small) ----------
__global__ __launch_bounds__(256) void ctx_partial_kernel(
    const float* __restrict__ memory, const float* __restrict__ wts,
    float* __restrict__ part) {
    const int ci = blockIdx.x, b = blockIdx.y, tid = threadIdx.x;
    const float2* m2 = (const float2*)memory;
    float2 acc = {0.0f, 0.0f};
    const int t0 = ci * 100, t1 = t0 + 100;
    #pragma unroll 4
    for (int t = t0; t < t1; ++t) {
        float wgt = wts[b * T_SZ + t];
        float2 v = m2[((size_t)(b * T_SZ + t)) * 256 + tid];
        acc.x += wgt * v.x;
        acc.y += wgt * v.y;
    }
    ((float2*)part)[(b * 20 + ci) * 256 + tid] = acc;
}
__global__ __launch_bounds__(256) void ctx_reduce_kernel(
    const float* __restrict__ part, float* __restrict__ ctx) {
    const int b = blockIdx.x, tid = threadIdx.x;
    const float2* p2 = (const float2*)part;
    float2 acc = {0.0f, 0.0f};
    #pragma unroll
    for (int ci = 0; ci < 20; ++ci) {
        float2 v = p2[(b * 20 + ci) * 256 + tid];
        acc.x += v.x;
        acc.y += v.y;
    }
    ((float2*)ctx)[b * 256 + tid] = acc;
}

// ---------- launch ----------
extern "C" void kernel_launch(void* const* d_in, const int* in_sizes, int n_in,
                              void* d_out, int out_size, void* d_ws, size_t ws_size,
                              hipStream_t stream) {
    const float* ahs    = (const float*)d_in[0];
    const float* memory = (const float*)d_in[1];
    const float* awcat  = (const float*)d_in[2];
    const float* Wq     = (const float*)d_in[3];
    const float* Wm     = (const float*)d_in[4];
    const float* Wv     = (const float*)d_in[5];
    const float* Wconv  = (const float*)d_in[6];
    const float* Wl     = (const float*)d_in[7];

    float* out = (float*)d_out;
    float* ctx = out;                 // [64][512]
    float* wts = out + B_SZ * MD;     // [64][2000]

    char* ws = (char*)d_ws;
    float* pq             = (float*)(ws);                    // 32 KB
    unsigned short* WB    = (unsigned short*)(ws + 32768);   // 128 KB
    unsigned short* WL    = (unsigned short*)(ws + 163840);  // 8 KB
    float* mloc           = (float*)(ws + 172032);           // 32 KB (64*125*4)
    float* Stile          = (float*)(ws + 204800);           // 32 KB
    float* ctile          = (float*)(ws + 237568);           // 16.4 MB
    float* part           = (float*)(ws + 237568);           // fallback 2.62 MB

    const size_t need_fused = 237568 + (size_t)B_SZ * NTILE * MD * 4;
    const int do_fuse = (ws_size >= need_fused) ? 1 : 0;

    prep_kernel<<<81, 512, 0, stream>>>(ahs, Wq, Wm, Wl, pq, WB, WL);
    energy_kernel<<<dim3(NTILE, B_SZ), 256, 0, stream>>>(
        memory, awcat, Wconv, Wv, pq, WB, WL, wts, ctile, mloc, Stile, do_fuse);
    finalize_kernel<<<dim3(B_SZ, 2), 256, 0, stream>>>(
        mloc, Stile, ctile, wts, ctx, do_fuse);
    if (!do_fuse) {
        ctx_partial_kernel<<<dim3(20, B_SZ), 256, 0, stream>>>(memory, wts, part);
        ctx_reduce_kernel<<<B_SZ, 256, 0, stream>>>(part, ctx);
    }
}